// Round 12
// baseline (202.261 us; speedup 1.0000x reference)
//
#include <hip/hip_runtime.h>

typedef float  f32x4 __attribute__((ext_vector_type(4)));
typedef __fp16 f16x2 __attribute__((ext_vector_type(2)));

#define T_LEN 2048
#define GROUP 16
#define NG    (T_LEN / GROUP)      /* 128 groups */
#define NT    (NG + 3)             /* 131 ticks, 4-stage lockstep pipeline */
#define KH    28.853901f           /* 20*log2(e) */

/* 1/(1+exp2(z)) */
__device__ __forceinline__ float hs_neg(float z) {
    float e = __builtin_amdgcn_exp2f(z);
    return __builtin_amdgcn_rcpf(1.0f + e);
}

#define WAITV(N) asm volatile("s_waitcnt vmcnt(" #N ")" ::: "memory")
#define WAITL()  asm volatile("s_waitcnt lgkmcnt(0)" ::: "memory")
/* raw barrier (NOT __syncthreads: that drains vmcnt(0), killing DMA prefetch) */
#define TICK_BARRIER() do {                                   \
    asm volatile("s_waitcnt lgkmcnt(0)" ::: "memory");        \
    __builtin_amdgcn_s_barrier();                             \
    __builtin_amdgcn_sched_barrier(0); } while (0)

/* one 16-step group = 12 f32x4 per lane (48 floats); per-lane global src */
#define DMA_GROUP(PIPE, SLOT, G) do {                                          \
    const float* g_ = row + (size_t)(G) * 48;                                  \
    _Pragma("unroll")                                                          \
    for (int j_ = 0; j_ < 12; ++j_) {                                          \
        __builtin_amdgcn_global_load_lds(                                      \
            (const __attribute__((address_space(1))) void*)(g_ + 4 * j_),      \
            (__attribute__((address_space(3))) void*)&s_in[PIPE][SLOT][j_][0], \
            16, 0, 0);                                                         \
    } } while (0)

__global__ __launch_bounds__(512, 1)
void xaj_dual_kernel(const float* __restrict__ inp,
                     const float* __restrict__ p_wum,
                     const float* __restrict__ p_wlm,
                     const float* __restrict__ p_wdm,
                     const float* __restrict__ p_c,
                     const float* __restrict__ p_b,
                     const float* __restrict__ p_k1,
                     const float* __restrict__ p_k2,
                     const float* __restrict__ p_k3,
                     float* __restrict__ out)
{
    /* TWO independent 4-wave pipelines per block (pipe = wave>>2), sharing
       the tick barrier. Wave i -> SIMD i%4, so A.Wk and B.Wk co-reside on
       one SIMD and hide each other's transcendental dependency stalls.
       Rings per pipe (all barrier-separated, audited):
         s_in ring-2 (prefetch 1 tick ahead), krem/kd1 ring-2 (W0->W1 lag 1),
         ku/kd2 ring-2 (W1->W2 lag 1), kwd f16 ring-2 (W2->W3 lag 1),
         wup ring-4 (W0->W3 lag 3). */
    __shared__ f32x4        s_in  [2][2][12][64];      /* 49152 B */
    __shared__ float        s_krem[2][2][GROUP][64];   /* 16384 B */
    __shared__ float        s_kd1 [2][2][GROUP][64];   /* 16384 B */
    __shared__ float        s_ku  [2][2][GROUP][64];   /* 16384 B */
    __shared__ float        s_kd2 [2][2][GROUP][64];   /* 16384 B */
    __shared__ __fp16       s_kwd [2][2][GROUP][64];   /*  8192 B */
    __shared__ unsigned int s_wup [2][4][GROUP][64];   /* 32768 B */

    const int lane  = threadIdx.x & 63;
    const int wv    = threadIdx.x >> 6;        /* 0..7 */
    const int pipe  = wv >> 2;                 /* 0,1  */
    const int stage = wv & 3;                  /* 0..3 */
    const int chain = blockIdx.x * 128 + pipe * 64 + lane;
    const float* __restrict__ row = inp + (size_t)chain * (3 * T_LEN);
    float* __restrict__ orow      = out + (size_t)chain * T_LEN;

    const float wum = p_wum[0], wlm = p_wlm[0], wdm = p_wdm[0];
    const float cc  = p_c[0],   bb  = p_b[0];
    const float k1  = p_k1[0],  k2  = p_k2[0],  k3 = p_k3[0];

    /* runoff_production called as (wu, wd, wl, p, wum, wdm, wlm, b, c) */
    const float w_total = (wum * 19.9f + 0.1f)
                        + (wdm * 30.0f + 60.0f)
                        + (wlm * 60.0f + 60.0f);
    const float inv_wt = 1.0f / w_total;
    const float c_s = cc * 0.19f + 0.01f;
    const float b_s = bb * 0.3f  + 0.1f;
    const float k1s = k1 * 0.69f + 0.01f;
    const float k2s = k2 * 0.69f + 0.01f;
    const float k3s = k3 * 0.89f + 0.01f;
    const float Kq = k1s + 0.5f * k2s * (1.0f - k1s)
                   + 0.25f * k3s * (1.0f - k1s) * (1.0f - k2s);
    const float C1 = inv_wt / KH;              /* un-K-scale inside ratio */

    float Kst = 0.0f;                          /* K-scaled scan state per wave */

    if (stage == 0) DMA_GROUP(pipe, 0, 0);     /* prologue: group 0 */

#pragma clang loop unroll(disable)
    for (int T = 0; T < NT; ++T) {
        if (stage == 0) {
            /* ---- W0: wu-chain. Kwu' = Kp - arg*a, arg = KHpet - Kwu ---- */
            if (T < NG) {
                const int g = T;
                WAITV(0);                      /* group g's DMA (issued T-1) */
                f32x4 fv[12];
#pragma unroll
                for (int j = 0; j < 12; ++j) fv[j] = s_in[pipe][g & 1][j][lane];
                WAITL();                       /* reads done before slot reuse */
                __builtin_amdgcn_sched_barrier(0);
                if (g + 1 < NG) DMA_GROUP(pipe, (g + 1) & 1, g + 1);
                float Kwu = Kst;
#pragma unroll
                for (int j = 0; j < GROUP; ++j) {
                    const int k0 = 3 * j, k2i = 3 * j + 2;
                    float pet = fv[k0 >> 2][k0 & 3];
                    float p   = fv[k2i >> 2][k2i & 3];
                    float KHpet = KH * pet, Kp = KH * p;
                    float arg  = KHpet - Kwu;            /* chain head */
                    float a    = hs_neg(arg);            /* h(wu-pet) */
                    float Kwun = fmaf(-arg, a, Kp);      /* chain tail */
                    float Kd1  = Kwun - Kwu;
                    float Ky   = arg + (Kwun - Kp);      /* = arg*(1-a) */
                    float hx   = hs_neg(-Ky);            /* h(pet-et1), ILP */
                    float Krem = hx * Ky;
                    s_krem[pipe][g & 1][j][lane] = Krem;
                    s_kd1 [pipe][g & 1][j][lane] = Kd1;
                    f16x2 pk = __builtin_amdgcn_cvt_pkrtz(Kwun, p);
                    s_wup[pipe][g & 3][j][lane] =
                        __builtin_bit_cast(unsigned int, pk);
                    Kwu = Kwun;
                }
                Kst = Kwu;
            }
        } else if (stage == 1) {
            /* ---- W1: wl-chain. Kwl' = A - b2*harg ---- */
            if (T >= 1 && T <= NG) {
                const int g = T - 1;
                float Kwl = Kst;
#pragma unroll
                for (int j = 0; j < GROUP; ++j) {
                    float Krem = s_krem[pipe][g & 1][j][lane];
                    float Kd1  = s_kd1 [pipe][g & 1][j][lane];
                    float hrem = hs_neg(-Krem);          /* h(rem), ILP */
                    float S    = Kwl + Kd1;
                    float A    = fmaf(-hrem, Krem, S);
                    float arg  = Kwl - Krem;             /* chain head */
                    float b2   = hs_neg(arg);            /* h(rem-wl) */
                    float harg = hrem * arg;
                    float Kwln = fmaf(-b2, harg, A);     /* chain tail */
                    float Ket2 = S - Kwln;
                    s_ku [pipe][g & 1][j][lane] = Krem - Ket2;
                    s_kd2[pipe][g & 1][j][lane] = Kd1 - Ket2;
                    Kwl = Kwln;
                }
                Kst = Kwl;
            }
        } else if (stage == 2) {
            /* ---- W2: wd-chain. Kwd' = A2 - c2*harg ---- */
            if (T >= 2 && T <= NG + 1) {
                const int g = T - 2;
                float Kwd = Kst;
#pragma unroll
                for (int j = 0; j < GROUP; ++j) {
                    float Ku  = s_ku [pipe][g & 1][j][lane];
                    float Kd2 = s_kd2[pipe][g & 1][j][lane];
                    float hu  = hs_neg(-Ku);             /* h(u), ILP */
                    float S2  = Kwd + Kd2;
                    float A2  = fmaf(-hu, Ku, S2);
                    float arg = Kwd - Ku;                /* chain head */
                    float c2v = hs_neg(arg);             /* h(u-wd) */
                    float harg = hu * arg;
                    float Kwdn = fmaf(-c2v, harg, A2);   /* chain tail */
                    s_kwd[pipe][g & 1][j][lane] = (__fp16)Kwdn;
                    Kwd = Kwdn;
                }
                Kst = Kwd;
            }
        } else {
            /* ---- W3: stateless output ---- */
            if (T >= 3) {
                const int g = T - 3;
                float qv[GROUP];
#pragma unroll
                for (int j = 0; j < GROUP; ++j) {
                    unsigned int pw = s_wup[pipe][g & 3][j][lane];
                    f16x2 pk = __builtin_bit_cast(f16x2, pw);
                    float Kwu_ = (float)pk[0];
                    float p    = (float)pk[1];
                    float Kwd_ = (float)s_kwd[pipe][g & 1][j][lane];
                    float ru = Kwu_ * C1;
                    float rd = Kwd_ * C1;
                    float s2v = fmaf(c_s * ru, ru, (b_s * rd) * rd);
                    float ps = p - s2v;
                    float so = hs_neg(-KH * ps);         /* h(ps) */
                    qv[j] = ps * so * Kq;
                }
                f32x4* o4 = (f32x4*)(orow + (size_t)g * GROUP);
#pragma unroll
                for (int i = 0; i < GROUP / 4; ++i) {
                    f32x4 q = {qv[4*i], qv[4*i+1], qv[4*i+2], qv[4*i+3]};
                    o4[i] = q;
                }
            }
        }
        TICK_BARRIER();
    }
}

extern "C" void kernel_launch(void* const* d_in, const int* in_sizes, int n_in,
                              void* d_out, int out_size, void* d_ws, size_t ws_size,
                              hipStream_t stream) {
    const float* inp = (const float*)d_in[0];
    const int B = out_size / T_LEN;            // 4096
    dim3 block(512), grid(B / 128);            // 32 blocks, 2 pipelines each
    xaj_dual_kernel<<<grid, block, 0, stream>>>(
        inp,
        (const float*)d_in[1],  // wum
        (const float*)d_in[2],  // wlm
        (const float*)d_in[3],  // wdm
        (const float*)d_in[4],  // c
        (const float*)d_in[5],  // b
        (const float*)d_in[6],  // k1
        (const float*)d_in[7],  // k2
        (const float*)d_in[8],  // k3
        (float*)d_out);
}

// Round 13
// 148.862 us; speedup vs baseline: 1.3587x; 1.3587x over previous
//
#include <hip/hip_runtime.h>

typedef float  f32x2 __attribute__((ext_vector_type(2)));
typedef float  f32x4 __attribute__((ext_vector_type(4)));
typedef __fp16 f16x2 __attribute__((ext_vector_type(2)));

#define T_LEN 2048
#define GROUP 16
#define NG    (T_LEN / GROUP)      /* 128 groups */
#define NT    (NG + 3)             /* 131 ticks, 4-stage lockstep pipeline */
#define KH    28.853901f           /* 20*log2(e) */

/* 1/(1+exp2(z)) */
__device__ __forceinline__ float hs_neg(float z) {
    float e = __builtin_amdgcn_exp2f(z);
    return __builtin_amdgcn_rcpf(1.0f + e);
}

#define WAITV(N) asm volatile("s_waitcnt vmcnt(" #N ")" ::: "memory")
/* raw barrier (NOT __syncthreads: that drains vmcnt(0), killing DMA prefetch) */
#define TICK_BARRIER() do {                                   \
    asm volatile("s_waitcnt lgkmcnt(0)" ::: "memory");        \
    __builtin_amdgcn_s_barrier();                             \
    __builtin_amdgcn_sched_barrier(0); } while (0)

/* one 16-step group = 12 f32x4 per lane; wave-uniform LDS base + lane*16 */
#define DMA_GROUP(SLOT, G) do {                                                \
    const float* g_ = row + (size_t)(G) * 48;                                  \
    _Pragma("unroll")                                                          \
    for (int j_ = 0; j_ < 12; ++j_) {                                          \
        __builtin_amdgcn_global_load_lds(                                      \
            (const __attribute__((address_space(1))) void*)(g_ + 4 * j_),      \
            (__attribute__((address_space(3))) void*)&s_in[SLOT][j_][0],       \
            16, 0, 0);                                                         \
    } } while (0)

__global__ __launch_bounds__(256, 1)
void xaj_bal_kernel(const float* __restrict__ inp,
                    const float* __restrict__ p_wum,
                    const float* __restrict__ p_wlm,
                    const float* __restrict__ p_wdm,
                    const float* __restrict__ p_c,
                    const float* __restrict__ p_b,
                    const float* __restrict__ p_k1,
                    const float* __restrict__ p_k2,
                    const float* __restrict__ p_k3,
                    float* __restrict__ out)
{
    /* Lockstep tick T: W3.pre -> group T+1 | W0 -> T | W1 -> T-1 | W2 -> T-2
       | W3.out -> T-3. W3 owns DMA + vmcnt + input K-scaling + output.
       Rings (audited, all barrier-separated):
         s_in ring-3 (read T+1, in-flight T+2, issue T+3)
         s_pp ring-2 (W3.pre T+1 -> W0 T)          kremd1 ring-2 (W0 -> W1)
         kud2 ring-2 (W1 -> W2)   kwd ring-2 (W2 -> W3.out, lag 1)
         wup ring-4 (W0 -> W3.out, lag 3) */
    __shared__ f32x4        s_in    [3][12][64];     /* 36864 B */
    __shared__ f32x2        s_pp    [2][GROUP][64];  /* 16384 B (KHpet, Kp) */
    __shared__ f32x2        s_kremd1[2][GROUP][64];  /* 16384 B (Krem, Kd1) */
    __shared__ f32x2        s_kud2  [2][GROUP][64];  /* 16384 B (Ku, Kd2)  */
    __shared__ __fp16       s_kwd   [2][GROUP][64];  /*  4096 B */
    __shared__ unsigned int s_wup   [4][GROUP][64];  /* 16384 B (f16 Kwu|Kp) */

    const int lane  = threadIdx.x & 63;
    const int wv    = threadIdx.x >> 6;        /* 0..3 */
    const int chain = blockIdx.x * 64 + lane;
    const float* __restrict__ row = inp + (size_t)chain * (3 * T_LEN);
    float* __restrict__ orow      = out + (size_t)chain * T_LEN;

    const float wum = p_wum[0], wlm = p_wlm[0], wdm = p_wdm[0];
    const float cc  = p_c[0],   bb  = p_b[0];
    const float k1  = p_k1[0],  k2  = p_k2[0],  k3 = p_k3[0];

    /* runoff_production called as (wu, wd, wl, p, wum, wdm, wlm, b, c) */
    const float w_total = (wum * 19.9f + 0.1f)
                        + (wdm * 30.0f + 60.0f)
                        + (wlm * 60.0f + 60.0f);
    const float inv_wt = 1.0f / w_total;
    const float c_s = cc * 0.19f + 0.01f;
    const float b_s = bb * 0.3f  + 0.1f;
    const float k1s = k1 * 0.69f + 0.01f;
    const float k2s = k2 * 0.69f + 0.01f;
    const float k3s = k3 * 0.89f + 0.01f;
    const float Kq = k1s + 0.5f * k2s * (1.0f - k1s)
                   + 0.25f * k3s * (1.0f - k1s) * (1.0f - k2s);
    const float C1    = inv_wt / KH;           /* un-K-scale wu,wd */
    const float invKH = 1.0f / KH;             /* un-K-scale p     */

    float Kst = 0.0f;                          /* K-scaled scan state per wave */

    if (wv == 3) {
        /* prologue: DMA 0,1; preprocess group 0; issue DMA 2 */
        DMA_GROUP(0, 0);
        DMA_GROUP(1, 1);
        WAITV(12);                             /* group 0 landed */
        __builtin_amdgcn_sched_barrier(0);
        f32x4 fv[12];
#pragma unroll
        for (int j = 0; j < 12; ++j) fv[j] = s_in[0][j][lane];
#pragma unroll
        for (int j = 0; j < GROUP; ++j) {
            const int k0 = 3 * j, k2i = 3 * j + 2;
            f32x2 pp = {KH * fv[k0 >> 2][k0 & 3], KH * fv[k2i >> 2][k2i & 3]};
            s_pp[0][j][lane] = pp;
        }
        DMA_GROUP(2, 2);
    }
    TICK_BARRIER();

#pragma clang loop unroll(disable)
    for (int T = 0; T < NT; ++T) {
        if (wv == 0) {
            /* ---- W0: wu-chain. Kwu' = Kp - arg*a, arg = KHpet - Kwu ---- */
            if (T < NG) {
                const int g = T;
                f32x2 ppv[GROUP];
#pragma unroll
                for (int j = 0; j < GROUP; ++j) ppv[j] = s_pp[g & 1][j][lane];
                float Kwu = Kst;
#pragma unroll
                for (int j = 0; j < GROUP; ++j) {
                    float KHpet = ppv[j][0], Kp = ppv[j][1];
                    float arg  = KHpet - Kwu;            /* chain head */
                    float a    = hs_neg(arg);            /* h(wu-pet) */
                    float Kwun = fmaf(-arg, a, Kp);      /* chain tail */
                    float Kd1  = Kwun - Kwu;
                    float Ky   = arg + (Kwun - Kp);      /* = arg*(1-a) */
                    float hx   = hs_neg(-Ky);            /* h(pet-et1), ILP */
                    float Krem = hx * Ky;
                    f32x2 kd = {Krem, Kd1};
                    s_kremd1[g & 1][j][lane] = kd;
                    f16x2 pk = __builtin_amdgcn_cvt_pkrtz(Kwun, Kp);
                    s_wup[g & 3][j][lane] = __builtin_bit_cast(unsigned int, pk);
                    Kwu = Kwun;
                }
                Kst = Kwu;
            }
        } else if (wv == 1) {
            /* ---- W1: wl-chain. Kwl' = A - b2*harg ---- */
            if (T >= 1 && T <= NG) {
                const int g = T - 1;
                f32x2 kd[GROUP];
#pragma unroll
                for (int j = 0; j < GROUP; ++j) kd[j] = s_kremd1[g & 1][j][lane];
                float Kwl = Kst;
#pragma unroll
                for (int j = 0; j < GROUP; ++j) {
                    float Krem = kd[j][0], Kd1 = kd[j][1];
                    float hrem = hs_neg(-Krem);          /* h(rem), ILP */
                    float S    = Kwl + Kd1;
                    float A    = fmaf(-hrem, Krem, S);
                    float arg  = Kwl - Krem;             /* chain head */
                    float b2   = hs_neg(arg);            /* h(rem-wl) */
                    float harg = hrem * arg;
                    float Kwln = fmaf(-b2, harg, A);     /* chain tail */
                    float Ket2 = S - Kwln;
                    f32x2 ud = {Krem - Ket2, Kd1 - Ket2};
                    s_kud2[g & 1][j][lane] = ud;
                    Kwl = Kwln;
                }
                Kst = Kwl;
            }
        } else if (wv == 2) {
            /* ---- W2: wd-chain. Kwd' = A2 - c2*harg ---- */
            if (T >= 2 && T <= NG + 1) {
                const int g = T - 2;
                f32x2 ud[GROUP];
#pragma unroll
                for (int j = 0; j < GROUP; ++j) ud[j] = s_kud2[g & 1][j][lane];
                float Kwd = Kst;
#pragma unroll
                for (int j = 0; j < GROUP; ++j) {
                    float Ku = ud[j][0], Kd2 = ud[j][1];
                    float hu  = hs_neg(-Ku);             /* h(u), ILP */
                    float S2  = Kwd + Kd2;
                    float A2  = fmaf(-hu, Ku, S2);
                    float arg = Kwd - Ku;                /* chain head */
                    float c2v = hs_neg(arg);             /* h(u-wd) */
                    float harg = hu * arg;
                    float Kwdn = fmaf(-c2v, harg, A2);   /* chain tail */
                    s_kwd[g & 1][j][lane] = (__fp16)Kwdn;
                    Kwd = Kwdn;
                }
                Kst = Kwd;
            }
        } else {
            /* ---- W3: input preprocess (T+1) + DMA + output (T-3) ---- */
            if (T + 1 < NG) {
                /* FIFO: [DMA(T+1) x12, DMA(T+2) x12, stores x4(if any)];
                   keep newest 12 -> drains DMA(T+1); DMA(T+2) mostly landed. */
                WAITV(12);
                __builtin_amdgcn_sched_barrier(0);
                const int gp = T + 1;
                f32x4 fv[12];
#pragma unroll
                for (int j = 0; j < 12; ++j) fv[j] = s_in[gp % 3][j][lane];
#pragma unroll
                for (int j = 0; j < GROUP; ++j) {
                    const int k0 = 3 * j, k2i = 3 * j + 2;
                    f32x2 pp = {KH * fv[k0 >> 2][k0 & 3],
                                KH * fv[k2i >> 2][k2i & 3]};
                    s_pp[gp & 1][j][lane] = pp;
                }
                if (T + 3 < NG) DMA_GROUP((T + 3) % 3, T + 3);
            }
            if (T >= 3) {
                const int g = T - 3;
                float qv[GROUP];
#pragma unroll
                for (int j = 0; j < GROUP; ++j) {
                    unsigned int pw = s_wup[g & 3][j][lane];
                    f16x2 pk = __builtin_bit_cast(f16x2, pw);
                    float Kwu_ = (float)pk[0];
                    float p    = (float)pk[1] * invKH;
                    float Kwd_ = (float)s_kwd[g & 1][j][lane];
                    float ru = Kwu_ * C1;
                    float rd = Kwd_ * C1;
                    float s2v = fmaf(c_s * ru, ru, (b_s * rd) * rd);
                    float ps = p - s2v;
                    float so = hs_neg(-KH * ps);         /* h(ps) */
                    qv[j] = ps * so * Kq;
                }
                f32x4* o4 = (f32x4*)(orow + (size_t)g * GROUP);
#pragma unroll
                for (int i = 0; i < GROUP / 4; ++i) {
                    f32x4 q = {qv[4*i], qv[4*i+1], qv[4*i+2], qv[4*i+3]};
                    o4[i] = q;
                }
            }
        }
        TICK_BARRIER();
    }
}

extern "C" void kernel_launch(void* const* d_in, const int* in_sizes, int n_in,
                              void* d_out, int out_size, void* d_ws, size_t ws_size,
                              hipStream_t stream) {
    const float* inp = (const float*)d_in[0];
    const int B = out_size / T_LEN;            // 4096
    dim3 block(256), grid(B / 64);             // 64 blocks, 4-wave pipeline
    xaj_bal_kernel<<<grid, block, 0, stream>>>(
        inp,
        (const float*)d_in[1],  // wum
        (const float*)d_in[2],  // wlm
        (const float*)d_in[3],  // wdm
        (const float*)d_in[4],  // c
        (const float*)d_in[5],  // b
        (const float*)d_in[6],  // k1
        (const float*)d_in[7],  // k2
        (const float*)d_in[8],  // k3
        (float*)d_out);
}